// Round 9
// baseline (57.183 us; speedup 1.0000x reference)
//
#include <hip/hip_runtime.h>
#include <stdint.h>

#define N_PROP 2000
#define NCLS 80
#define MAXPC 100
#define MAXIMG 300
#define NFLAT (NCLS*MAXPC)   // 8000
#define MAXNB 32
#define CAP 768              // select_topt candidate cap (fallback path)
#define CAPG 2000            // global fast-path candidate cap
#define TKEY 0xBF7F0000u     // fkey(0.99609375): fast-path candidate threshold
#define FKEY_NEGINF 0x007FFFFFu

#define ST_UNDEC 0
#define ST_KEPT 1
#define ST_SUPP 2

// persistent device scratch (rewritten every launch -> deterministic)
__device__ float4   g_boxes[N_PROP];
__device__ uint32_t g_adj[N_PROP * 64];
__device__ int      g_deg[N_PROP];
__device__ int      g_nbr[N_PROP * MAXNB];
__device__ __align__(16) uint32_t g_outkey[NFLAT];          // fallback only
__device__ int      g_outidx[NFLAT];                        // fallback only
__device__ __align__(16) float g_scoresT[NCLS * N_PROP];
__device__ __align__(16) unsigned char g_state[NCLS * N_PROP];
__device__ uint64_t g_scand[CAPG];      // global candidates (packed key,c,i)
__device__ int      g_scount;
__device__ int      g_done;

__device__ __forceinline__ uint32_t fkey(float f) {
    uint32_t u = __float_as_uint(f);
    return (u & 0x80000000u) ? ~u : (u | 0x80000000u);
}
// 2048 bins of width 2^5 over [TKEY, fkey(1.0)); only called with k >= TKEY
__device__ __forceinline__ uint32_t cbin2(uint32_t k) {
    uint32_t b = (k - TKEY) >> 5;
    return b > 2047u ? 2047u : b;
}
__device__ __forceinline__ uint64_t packe(uint32_t key, int c, int i) {
    return ((uint64_t)key << 18) | ((uint32_t)(127 - c) << 11) | (uint32_t)(2047 - i);
}

// 125 blocks x 1024: decode boxes to LDS, wave-per-row IoU bits (16 rows/blk),
// score transpose. Block 0 persists g_boxes and resets counters.
__global__ __launch_bounds__(1024) void adj_kernel(const float* __restrict__ deltas,
                                                   const float* __restrict__ props,
                                                   const float* __restrict__ scores) {
    __shared__ float4 bb[N_PROP];
    const int tid = threadIdx.x;
    const float4* p4 = (const float4*)props;
    const float4* d4 = (const float4*)deltas;
    for (int i = tid; i < N_PROP; i += 1024) {
        float4 p = p4[i], d = d4[i];
        float w = p.z - p.x + 1.0f, h = p.w - p.y + 1.0f;
        float cx = p.x + 0.5f*w,  cy = p.y + 0.5f*h;
        float pcx = d.x*w + cx, pcy = d.y*h + cy;
        float pw = expf(d.z)*w, ph = expf(d.w)*h;
        bb[i] = make_float4(pcx - 0.5f*pw, pcy - 0.5f*ph, pcx + 0.5f*pw, pcy + 0.5f*ph);
    }
    {
        int base = blockIdx.x * 1280;       // 125 * 1280 = 160000
        for (int q = tid; q < 1280; q += 1024) {
            int flat = base + q;
            float v = scores[flat];
            g_scoresT[(flat % NCLS) * N_PROP + (flat / NCLS)] = v;
        }
    }
    if (blockIdx.x == 0 && tid == 0) { g_done = 0; g_scount = 0; }
    __syncthreads();
    if (blockIdx.x == 0) {
        for (int i = tid; i < N_PROP; i += 1024) g_boxes[i] = bb[i];
    }
    const int row = blockIdx.x * 16 + (tid >> 6);
    const int lane = tid & 63;
    float4 bi = bb[row];
    float ai = fmaxf(bi.z - bi.x, 0.0f) * fmaxf(bi.w - bi.y, 0.0f);
    uint32_t bits = 0u;
    #pragma unroll 8
    for (int b = 0; b < 32; ++b) {
        int j = lane * 32 + b;
        if (j < N_PROP && j != row) {
            float4 bj = bb[j];
            float aj = fmaxf(bj.z - bj.x, 0.0f) * fmaxf(bj.w - bj.y, 0.0f);
            float ix1 = fmaxf(bi.x, bj.x);
            float iy1 = fmaxf(bi.y, bj.y);
            float ix2 = fminf(bi.z, bj.z);
            float iy2 = fminf(bi.w, bj.w);
            float inter = fmaxf(ix2 - ix1, 0.0f) * fmaxf(iy2 - iy1, 0.0f);
            float uni = ai + aj - inter;
            if (inter > 0.7f * uni) bits |= (1u << b);
        }
    }
    g_adj[row * 64 + lane] = bits;
    int cnt = __popc(bits);
    int incl = cnt;
    for (int off = 1; off < 64; off <<= 1) {
        int v = __shfl_up(incl, off);
        if (lane >= off) incl += v;
    }
    int base = incl - cnt;
    if (lane == 63) g_deg[row] = incl;
    uint32_t t = bits; int k = 0;
    while (t) {
        int b = __ffs(t) - 1; t &= t - 1;
        int s = base + k; ++k;
        if (s < MAXNB) g_nbr[row * MAXNB + s] = lane * 32 + b;
    }
}

// select_topt (round-8 proven, 1024 threads) — used by FALLBACK only.
__device__ void select_topt(const uint32_t* __restrict__ skey,
                            const unsigned char* state, int want,
                            int n, int t,
                            uint32_t* hist, uint32_t* binFill,
                            uint64_t* cand, uint64_t* outbuf, int* sh) {
    const int tid = threadIdx.x;
    const int lane = tid & 63;
    uint32_t prefix = 0, above = 0, thr = 0, Bi = 0, mask = 0x7FFu;
    int shift = 21, width = 11;
    bool tie = false;
    for (;;) {
        for (int b = tid; b <= 2048; b += 1024) hist[b] = 0;
        __syncthreads();
        for (int i0 = 0; i0 < n; i0 += 1024) {
            int i = i0 + tid;
            bool valid = false; uint32_t b = 0;
            if (i < n && (!state || state[i] == want)) {
                uint32_t k = skey[i];
                if (shift == 21 || (k >> (shift + width)) == prefix) {
                    valid = true; b = (k >> shift) & mask;
                }
            }
            uint32_t b0 = __shfl(b, 0);
            bool same = valid && (b == b0);
            unsigned long long eq = __ballot(same);
            if (eq == ~0ull) {
                if (lane == 0) atomicAdd(&hist[b0], 64u);
            } else if (valid) {
                atomicAdd(&hist[b], 1u);
            }
        }
        __syncthreads();
        if (tid < 256) {
            uint32_t c8 = 0;
            #pragma unroll 8
            for (int q = 0; q < 8; ++q) c8 += hist[tid*8 + q];
            binFill[tid] = c8;
        }
        __syncthreads();
        if (tid < 64) {
            uint32_t h0=binFill[4*lane], h1=binFill[4*lane+1], h2=binFill[4*lane+2], h3=binFill[4*lane+3];
            uint32_t T = h0+h1+h2+h3, I = T;
            for (int off = 1; off < 64; off <<= 1) {
                uint32_t v = __shfl_down(I, off);
                if (lane + off < 64) I += v;
            }
            uint32_t S = I - T;
            uint32_t o3=h3+S, o2=h2+o3, o1=h1+o2, o0=h0+o1;
            binFill[4*lane]=o0; binFill[4*lane+1]=o1; binFill[4*lane+2]=o2; binFill[4*lane+3]=o3;
        }
        __syncthreads();
        if (tid < 256) {
            uint32_t run = (tid == 255) ? 0u : binFill[tid+1];
            uint32_t t7,t6,t5,t4,t3,t2,t1,t0;
            run += hist[tid*8+7]; t7 = run;
            run += hist[tid*8+6]; t6 = run;
            run += hist[tid*8+5]; t5 = run;
            run += hist[tid*8+4]; t4 = run;
            run += hist[tid*8+3]; t3 = run;
            run += hist[tid*8+2]; t2 = run;
            run += hist[tid*8+1]; t1 = run;
            run += hist[tid*8+0]; t0 = run;
            hist[tid*8+0]=t0; hist[tid*8+1]=t1; hist[tid*8+2]=t2; hist[tid*8+3]=t3;
            hist[tid*8+4]=t4; hist[tid*8+5]=t5; hist[tid*8+6]=t6; hist[tid*8+7]=t7;
        }
        __syncthreads();
        if (tid < 256) {
            #pragma unroll 8
            for (int q = 0; q < 8; ++q) {
                int b = tid*8 + q;
                uint32_t sb = hist[b], sb1 = hist[b+1];
                if (above + sb >= (uint32_t)t && above + sb1 < (uint32_t)t) sh[1] = b;
            }
        }
        __syncthreads();
        int B = sh[1];
        uint32_t nCand = above + hist[B];
        uint32_t nAbove = above + hist[B+1];
        thr = (prefix << width) | (uint32_t)B;
        if (nCand <= CAP) { __syncthreads(); break; }
        if (shift == 0) {
            uint32_t needS = (uint32_t)t - nAbove;
            __syncthreads();
            for (int b = tid; b < 257; b += 1024) hist[b] = 0;
            __syncthreads();
            for (int i = tid; i < n; i += 1024)
                if ((!state || state[i] == want) && skey[i] == thr)
                    atomicAdd(&hist[i >> 5], 1u);
            __syncthreads();
            if (tid < 64) {
                uint32_t h0=hist[4*lane], h1=hist[4*lane+1], h2=hist[4*lane+2], h3=hist[4*lane+3];
                uint32_t T = h0+h1+h2+h3, I = T;
                for (int off = 1; off < 64; off <<= 1) {
                    uint32_t v = __shfl_up(I, off);
                    if (lane >= off) I += v;
                }
                uint32_t S = I - T;
                uint32_t a0=S+h0, a1=a0+h1, a2=a1+h2, a3=a2+h3;
                hist[4*lane]=a0; hist[4*lane+1]=a1; hist[4*lane+2]=a2; hist[4*lane+3]=a3;
            }
            __syncthreads();
            if (tid < 256) {
                if (hist[tid] >= needS && (tid == 0 || hist[tid-1] < needS)) sh[1] = tid;
            }
            __syncthreads();
            Bi = (uint32_t)sh[1];
            tie = true;
            __syncthreads();
            break;
        }
        prefix = thr; above = nAbove;
        if (shift == 21) { shift = 10; width = 11; mask = 0x7FFu; }
        else             { shift = 0;  width = 10; mask = 0x3FFu; }
        __syncthreads();
    }

    if (!tie && above == 0) {
        for (int b = tid; b < 2048; b += 1024) binFill[b] = 0;
        __syncthreads();
        for (int i = tid; i < n; i += 1024) {
            if (!state || state[i] == want) {
                uint32_t k = skey[i];
                if ((k >> shift) >= thr) {
                    uint32_t be = (k >> shift) & mask;
                    uint32_t pos = hist[be+1] + atomicAdd(&binFill[be], 1u);
                    cand[pos] = ((uint64_t)k << 32) | (uint32_t)(0xFFFFFFFFu - (uint32_t)i);
                }
            }
        }
        __syncthreads();
        int m = (int)hist[thr & mask];
        for (int s = tid; s < m; s += 1024) {
            uint64_t e = cand[s];
            uint32_t k = (uint32_t)(e >> 32);
            uint32_t be = (k >> shift) & mask;
            uint32_t base = hist[be+1];
            uint32_t cnt = hist[be] - base;
            uint32_t r = base;
            for (uint32_t s2 = base; s2 < base + cnt; ++s2)
                r += (cand[s2] > e) ? 1u : 0u;
            if (r < (uint32_t)t) outbuf[r] = e;
        }
        __syncthreads();
    } else {
        if (tid == 0) sh[2] = 0;
        __syncthreads();
        for (int i0 = 0; i0 < n; i0 += 1024) {
            int i = i0 + tid;
            bool take = false; uint32_t k = 0;
            if (i < n && (!state || state[i] == want)) {
                k = skey[i];
                take = tie ? (k > thr || (k == thr && (uint32_t)(i >> 5) <= Bi))
                           : ((k >> shift) >= thr);
            }
            unsigned long long mm = __ballot(take);
            if (mm) {
                int leader = __ffsll((long long)mm) - 1;
                int wbase = 0;
                if (lane == leader) wbase = atomicAdd(&sh[2], (int)__popcll(mm));
                wbase = __shfl(wbase, leader);
                if (take) {
                    int pos = wbase + __popcll(mm & ((1ull << lane) - 1ull));
                    cand[pos] = ((uint64_t)k << 32) | (uint32_t)(0xFFFFFFFFu - (uint32_t)i);
                }
            }
        }
        __syncthreads();
        int m = sh[2];
        for (int s = tid; s < m; s += 1024) {
            uint64_t e = cand[s];
            uint32_t r = 0;
            for (int s2 = 0; s2 < m; ++s2) r += (cand[s2] > e) ? 1u : 0u;
            if (r < (uint32_t)t) outbuf[r] = e;
        }
        __syncthreads();
    }
}

// shared-memory layout (55.7 KB)
#define SM_A      0        // class: skey 0-8000 | state 8000-10016 | sdeg 10048-14048
                           // tail: scandLDS 0-16000 | cand2 16000-32000 ; fallback: gkey 0-32000
#define SM_HIST   32000    // 2052*4
#define SM_BINF   40208    // 2048*4
#define SM_OUT    48400    // 304*8
#define SM_SH     50832    // 64
#define SM_CAND   50896    // 768*8  (fallback select_topt)
#define SM_BYTES  57040

// 80 blocks x 1024: fixpoint NMS per class, append global candidates;
// last-finishing block ranks candidates and writes output (fast path),
// or runs the full fallback if guard conditions fail.
__global__ __launch_bounds__(1024) void nms_kernel(float* __restrict__ out) {
    __shared__ __align__(16) char smem[SM_BYTES];
    uint32_t* skey  = (uint32_t*)(smem + SM_A);
    unsigned char* state = (unsigned char*)(smem + SM_A + 8000);
    uint16_t* sdeg  = (uint16_t*)(smem + SM_A + 10048);
    uint32_t* hist  = (uint32_t*)(smem + SM_HIST);
    uint32_t* binF  = (uint32_t*)(smem + SM_BINF);
    uint64_t* outbuf= (uint64_t*)(smem + SM_OUT);
    int* sh         = (int*)(smem + SM_SH);
    uint64_t* cand  = (uint64_t*)(smem + SM_CAND);
    __shared__ int s_ch[3];
    __shared__ int s_cnt;
    const int c = blockIdx.x, tid = threadIdx.x;
    const int lane = tid & 63;

    if (tid < 500) {
        const float4* srow = (const float4*)&g_scoresT[c * N_PROP];
        float4 v = srow[tid];
        skey[4*tid+0] = fkey(v.x);
        skey[4*tid+1] = fkey(v.y);
        skey[4*tid+2] = fkey(v.z);
        skey[4*tid+3] = fkey(v.w);
        int4 d = ((const int4*)g_deg)[tid];
        sdeg[4*tid+0] = (uint16_t)d.x; state[4*tid+0] = d.x ? ST_UNDEC : ST_KEPT;
        sdeg[4*tid+1] = (uint16_t)d.y; state[4*tid+1] = d.y ? ST_UNDEC : ST_KEPT;
        sdeg[4*tid+2] = (uint16_t)d.z; state[4*tid+2] = d.z ? ST_UNDEC : ST_KEPT;
        sdeg[4*tid+3] = (uint16_t)d.w; state[4*tid+3] = d.w ? ST_UNDEC : ST_KEPT;
    }
    if (tid < 3) s_ch[tid] = 0;
    __syncthreads();

    // fixpoint: keep[i] <=> no adjacent better j with keep[j]  (== greedy NMS)
    int p = 0;
    for (;;) {
        s_ch[(p+1) % 3] = 0;
        for (int i = tid; i < N_PROP; i += 1024) {
            if (state[i] != ST_UNDEC) continue;
            uint32_t ki = skey[i];
            int deg = sdeg[i];
            bool anyKept = false, anyUndec = false;
            if (deg <= MAXNB) {
                for (int nn = 0; nn < deg; ++nn) {
                    int j = g_nbr[i * MAXNB + nn];
                    uint32_t kj = skey[j];
                    if (kj > ki || (kj == ki && j < i)) {
                        unsigned char stj = state[j];
                        if (stj == ST_KEPT) anyKept = true;
                        else if (stj == ST_UNDEC) anyUndec = true;
                    }
                }
            } else {
                for (int w = 0; w < 64; ++w) {
                    uint32_t bits = g_adj[i * 64 + w];
                    while (bits) {
                        int b = __ffs(bits) - 1; bits &= bits - 1;
                        int j = w * 32 + b;
                        uint32_t kj = skey[j];
                        if (kj > ki || (kj == ki && j < i)) {
                            unsigned char stj = state[j];
                            if (stj == ST_KEPT) anyKept = true;
                            else if (stj == ST_UNDEC) anyUndec = true;
                        }
                    }
                }
            }
            if (anyKept)        { state[i] = ST_SUPP; s_ch[p] = 1; }
            else if (!anyUndec) { state[i] = ST_KEPT; s_ch[p] = 1; }
        }
        __syncthreads();
        if (!s_ch[p]) break;
        p = (p + 1) % 3;
    }

    // persist state for the (never-expected) fallback
    if (tid < 500)
        ((uint32_t*)&g_state[c * N_PROP])[tid] = ((const uint32_t*)state)[tid];

    // append kept entries with key >= TKEY to the global candidate list
    for (int i0 = 0; i0 < N_PROP; i0 += 1024) {
        int i = i0 + tid;
        bool take = (i < N_PROP) && (state[i] == ST_KEPT) && (skey[i] >= TKEY);
        unsigned long long mm = __ballot(take);
        if (mm) {
            int leader = __ffsll((long long)mm) - 1;
            int wbase = 0;
            if (lane == leader) wbase = atomicAdd(&g_scount, (int)__popcll(mm));
            wbase = __shfl(wbase, leader);
            if (take) {
                int pos = wbase + __popcll(mm & ((1ull << lane) - 1ull));
                if (pos < CAPG) g_scand[pos] = packe(skey[i], c, i);
            }
        }
    }

    // ---- fan-in: last block to finish runs the tail ----
    __threadfence();
    __syncthreads();
    if (tid == 0) sh[3] = atomicAdd(&g_done, 1);
    __syncthreads();
    if (sh[3] != NCLS - 1) return;
    __threadfence();

    const int scount = g_scount;
    bool fastok = (scount >= MAXIMG && scount <= CAPG);

    if (fastok) {
        uint64_t* scand = (uint64_t*)(smem + SM_A);            // reuse (class arrays dead)
        uint64_t* cand2 = (uint64_t*)(smem + SM_A + 16000);
        for (int s = tid; s < scount; s += 1024) scand[s] = g_scand[s];
        for (int b = tid; b <= 2048; b += 1024) hist[b] = 0;
        __syncthreads();
        for (int s = tid; s < scount; s += 1024)
            atomicAdd(&hist[cbin2((uint32_t)(scand[s] >> 18))], 1u);
        __syncthreads();
        // suffix scan of hist[0..2047]
        if (tid < 256) {
            uint32_t c8 = 0;
            #pragma unroll 8
            for (int q = 0; q < 8; ++q) c8 += hist[tid*8 + q];
            binF[tid] = c8;
        }
        __syncthreads();
        if (tid < 64) {
            uint32_t h0=binF[4*lane], h1=binF[4*lane+1], h2=binF[4*lane+2], h3=binF[4*lane+3];
            uint32_t T = h0+h1+h2+h3, I = T;
            for (int off = 1; off < 64; off <<= 1) {
                uint32_t v = __shfl_down(I, off);
                if (lane + off < 64) I += v;
            }
            uint32_t S = I - T;
            uint32_t o3=h3+S, o2=h2+o3, o1=h1+o2, o0=h0+o1;
            binF[4*lane]=o0; binF[4*lane+1]=o1; binF[4*lane+2]=o2; binF[4*lane+3]=o3;
        }
        __syncthreads();
        if (tid < 256) {
            uint32_t run = (tid == 255) ? 0u : binF[tid+1];
            uint32_t t7,t6,t5,t4,t3,t2,t1,t0;
            run += hist[tid*8+7]; t7 = run;
            run += hist[tid*8+6]; t6 = run;
            run += hist[tid*8+5]; t5 = run;
            run += hist[tid*8+4]; t4 = run;
            run += hist[tid*8+3]; t3 = run;
            run += hist[tid*8+2]; t2 = run;
            run += hist[tid*8+1]; t1 = run;
            run += hist[tid*8+0]; t0 = run;
            hist[tid*8+0]=t0; hist[tid*8+1]=t1; hist[tid*8+2]=t2; hist[tid*8+3]=t3;
            hist[tid*8+4]=t4; hist[tid*8+5]=t5; hist[tid*8+6]=t6; hist[tid*8+7]=t7;
        }
        __syncthreads();
        if (tid < 256) {
            #pragma unroll 8
            for (int q = 0; q < 8; ++q) {
                int b = tid*8 + q;
                if (hist[b] >= (uint32_t)MAXIMG && hist[b+1] < (uint32_t)MAXIMG) sh[1] = b;
            }
        }
        __syncthreads();
        const int B = sh[1];
        const int nCand = (int)hist[B];
        for (int b = tid; b < 2048; b += 1024) binF[b] = 0;
        __syncthreads();
        for (int s = tid; s < scount; s += 1024) {
            uint64_t e = scand[s];
            uint32_t b = cbin2((uint32_t)(e >> 18));
            if (b >= (uint32_t)B) {
                uint32_t pos = hist[b+1] + atomicAdd(&binF[b], 1u);
                cand2[pos] = e;
            }
        }
        __syncthreads();
        for (int s = tid; s < nCand; s += 1024) {
            uint64_t e = cand2[s];
            uint32_t b = cbin2((uint32_t)(e >> 18));
            uint32_t base = hist[b+1];
            uint32_t cnt2 = hist[b] - base;
            uint32_t r = base;
            for (uint32_t s2 = base; s2 < base + cnt2; ++s2)
                r += (cand2[s2] > e) ? 1u : 0u;
            if (r < (uint32_t)MAXIMG) outbuf[r] = e;
        }
        __syncthreads();
        // per-class cap check over the 300 winners
        int* cc = (int*)binF;
        if (tid < NCLS) cc[tid] = 0;
        if (tid == 0) sh[4] = 0;
        __syncthreads();
        if (tid < MAXIMG) {
            int wc = 127 - (int)((outbuf[tid] >> 11) & 0x7F);
            atomicAdd(&cc[wc], 1);
        }
        __syncthreads();
        if (tid < NCLS && cc[tid] > MAXPC) sh[4] = 1;
        __syncthreads();
        if (!sh[4]) {
            if (tid < MAXIMG) {
                uint64_t e = outbuf[tid];
                int i = 2047 - (int)(e & 0x7FF);
                int wc = 127 - (int)((e >> 11) & 0x7F);
                float4 b = g_boxes[i];
                out[tid*4+0] = b.x;
                out[tid*4+1] = b.y;
                out[tid*4+2] = b.z;
                out[tid*4+3] = b.w;
                out[MAXIMG*4 + tid] = (float)wc;
            }
            return;
        }
        fastok = false;
        __syncthreads();
    }

    // ================== FALLBACK (correctness net; never runs on bench data) ==================
    // sequential per-class top-100 select, then full top-300 over 8000 entries.
    for (int c2 = 0; c2 < NCLS; ++c2) {
        if (tid < 500) {
            const float4* srow = (const float4*)&g_scoresT[c2 * N_PROP];
            float4 v = srow[tid];
            skey[4*tid+0] = fkey(v.x);
            skey[4*tid+1] = fkey(v.y);
            skey[4*tid+2] = fkey(v.z);
            skey[4*tid+3] = fkey(v.w);
            ((uint32_t*)state)[tid] = ((const uint32_t*)&g_state[c2 * N_PROP])[tid];
        }
        if (tid == 0) s_cnt = 0;
        __syncthreads();
        {
            int local = 0;
            for (int i = tid; i < N_PROP; i += 1024) local += (state[i] == ST_KEPT) ? 1 : 0;
            if (local) atomicAdd(&s_cnt, local);
        }
        __syncthreads();
        const int kept = s_cnt;
        const int t1 = kept < MAXPC ? kept : MAXPC;
        select_topt(skey, state, ST_KEPT, N_PROP, t1, hist, binF, cand, outbuf, sh);
        for (int r = tid; r < t1; r += 1024) {
            uint64_t e = outbuf[r];
            g_outkey[c2 * MAXPC + r] = (uint32_t)(e >> 32);
            g_outidx[c2 * MAXPC + r] = (int)(0xFFFFFFFFu - (uint32_t)e);
        }
        if (kept < MAXPC) {
            __syncthreads();
            const int t2 = MAXPC - kept;
            select_topt(skey, state, ST_SUPP, N_PROP, t2, hist, binF, cand, outbuf, sh);
            for (int r = tid; r < t2; r += 1024) {
                uint64_t e = outbuf[r];
                g_outkey[c2 * MAXPC + kept + r] = FKEY_NEGINF;
                g_outidx[c2 * MAXPC + kept + r] = (int)(0xFFFFFFFFu - (uint32_t)e);
            }
        }
        __syncthreads();
    }
    {
        uint32_t* gkey = (uint32_t*)(smem + SM_A);
        const uint4* gk4 = (const uint4*)g_outkey;
        uint4* lk4 = (uint4*)gkey;
        for (int q = tid; q < NFLAT/4; q += 1024) lk4[q] = gk4[q];
        __syncthreads();
        select_topt(gkey, nullptr, 0, NFLAT, MAXIMG, hist, binF, cand, outbuf, sh);
        for (int r = tid; r < MAXIMG; r += 1024) {
            uint64_t e = outbuf[r];
            int f = (int)(0xFFFFFFFFu - (uint32_t)e);
            int pi = g_outidx[f];
            float4 b = g_boxes[pi];
            out[r*4+0] = b.x;
            out[r*4+1] = b.y;
            out[r*4+2] = b.z;
            out[r*4+3] = b.w;
            out[MAXIMG*4 + r] = (float)(f / MAXPC);
        }
    }
}

extern "C" void kernel_launch(void* const* d_in, const int* in_sizes, int n_in,
                              void* d_out, int out_size, void* d_ws, size_t ws_size,
                              hipStream_t stream) {
    const float* deltas = (const float*)d_in[0];   // roi_bboxes_txtytwth [2000,4]
    const float* scores = (const float*)d_in[1];   // roi_score [2000,80]
    const float* props  = (const float*)d_in[2];   // rpn_proposals_bboxes [2000,4]
    float* out = (float*)d_out;                    // 1200 box floats + 300 class floats

    adj_kernel<<<125, 1024, 0, stream>>>(deltas, props, scores);
    nms_kernel<<<NCLS, 1024, 0, stream>>>(out);
}

// Round 10
// 36.159 us; speedup vs baseline: 1.5814x; 1.5814x over previous
//
#include <hip/hip_runtime.h>
#include <stdint.h>

#define N_PROP 2000
#define NCLS 80
#define MAXPC 100
#define MAXIMG 300
#define NFLAT (NCLS*MAXPC)   // 8000
#define MAXNB 32
#define CAP 768              // select_topt candidate cap (fallback path)
#define CAPT 768             // tail fast-path compaction cap
#define SLOT 32              // per-class candidate slots (SLOT < MAXPC => rank proof)
#define TKEY 0xBF7F0000u     // fkey(0.99609375): candidate threshold
#define FKEY_NEGINF 0x007FFFFFu

#define ST_UNDEC 0
#define ST_KEPT 1
#define ST_SUPP 2

// persistent device scratch (rewritten every launch -> deterministic)
__device__ float4   g_boxes[N_PROP];
__device__ uint32_t g_adj[N_PROP * 64];
__device__ int      g_deg[N_PROP];
__device__ int      g_nbr[N_PROP * MAXNB];
__device__ __align__(16) uint32_t g_outkey[NFLAT];          // fallback only
__device__ int      g_outidx[NFLAT];                        // fallback only
__device__ __align__(16) float g_scoresT[NCLS * N_PROP];
__device__ __align__(16) unsigned char g_state[NCLS * N_PROP];
__device__ uint64_t g_scand2[NCLS * SLOT];  // per-class candidate slots
__device__ int      g_ccnt[NCLS];           // per-class candidate counts
__device__ int      g_ovf;                  // any class overflowed SLOT

__device__ __forceinline__ uint32_t fkey(float f) {
    uint32_t u = __float_as_uint(f);
    return (u & 0x80000000u) ? ~u : (u | 0x80000000u);
}
// 2048 bins of width 2^5 over [TKEY, fkey(1.0)]; only called with k >= TKEY
__device__ __forceinline__ uint32_t cbin2(uint32_t k) {
    uint32_t b = (k - TKEY) >> 5;
    return b > 2047u ? 2047u : b;
}
// packed order == global tie-break order: key desc, class asc, index asc
__device__ __forceinline__ uint64_t packe(uint32_t key, int c, int i) {
    return ((uint64_t)key << 18) | ((uint32_t)(127 - c) << 11) | (uint32_t)(2047 - i);
}

// 125 blocks x 1024: decode boxes to LDS, wave-per-row IoU bits (16 rows/blk),
// LDS-staged score transpose. Block 0 persists g_boxes and resets g_ovf.
__global__ __launch_bounds__(1024) void adj_kernel(const float* __restrict__ deltas,
                                                   const float* __restrict__ props,
                                                   const float* __restrict__ scores) {
    __shared__ float4 bb[N_PROP];           // 32 KB
    __shared__ float tile[NCLS][17];        // 5.4 KB (pad 17 vs LDS bank conflicts)
    const int tid = threadIdx.x;
    const float4* p4 = (const float4*)props;
    const float4* d4 = (const float4*)deltas;
    for (int i = tid; i < N_PROP; i += 1024) {
        float4 p = p4[i], d = d4[i];
        float w = p.z - p.x + 1.0f, h = p.w - p.y + 1.0f;
        float cx = p.x + 0.5f*w,  cy = p.y + 0.5f*h;
        float pcx = d.x*w + cx, pcy = d.y*h + cy;
        float pw = expf(d.z)*w, ph = expf(d.w)*h;
        bb[i] = make_float4(pcx - 0.5f*pw, pcy - 0.5f*ph, pcx + 0.5f*pw, pcy + 0.5f*ph);
    }
    // transpose: coalesced read -> LDS tile -> 64B-chunk writes
    {
        int base_flat = blockIdx.x * 1280;      // 16 proposals x 80 classes
        for (int q = tid; q < 1280; q += 1024) {
            int i_loc = q / 80, c = q - i_loc * 80;
            tile[c][i_loc] = scores[base_flat + q];
        }
    }
    if (blockIdx.x == 0 && tid == 0) g_ovf = 0;
    __syncthreads();
    {
        int base_i = blockIdx.x * 16;
        for (int q = tid; q < 1280; q += 1024) {
            int c = q >> 4, e = q & 15;
            g_scoresT[c * N_PROP + base_i + e] = tile[c][e];
        }
    }
    if (blockIdx.x == 0) {
        for (int i = tid; i < N_PROP; i += 1024) g_boxes[i] = bb[i];
    }
    const int row = blockIdx.x * 16 + (tid >> 6);
    const int lane = tid & 63;
    float4 bi = bb[row];
    float ai = fmaxf(bi.z - bi.x, 0.0f) * fmaxf(bi.w - bi.y, 0.0f);
    uint32_t bits = 0u;
    #pragma unroll 8
    for (int b = 0; b < 32; ++b) {
        int j = lane * 32 + b;
        if (j < N_PROP && j != row) {
            float4 bj = bb[j];
            float aj = fmaxf(bj.z - bj.x, 0.0f) * fmaxf(bj.w - bj.y, 0.0f);
            float ix1 = fmaxf(bi.x, bj.x);
            float iy1 = fmaxf(bi.y, bj.y);
            float ix2 = fminf(bi.z, bj.z);
            float iy2 = fminf(bi.w, bj.w);
            float inter = fmaxf(ix2 - ix1, 0.0f) * fmaxf(iy2 - iy1, 0.0f);
            float uni = ai + aj - inter;
            if (inter > 0.7f * uni) bits |= (1u << b);
        }
    }
    g_adj[row * 64 + lane] = bits;
    int cnt = __popc(bits);
    int incl = cnt;
    for (int off = 1; off < 64; off <<= 1) {
        int v = __shfl_up(incl, off);
        if (lane >= off) incl += v;
    }
    int base = incl - cnt;
    if (lane == 63) g_deg[row] = incl;
    uint32_t t = bits; int k = 0;
    while (t) {
        int b = __ffs(t) - 1; t &= t - 1;
        int s = base + k; ++k;
        if (s < MAXNB) g_nbr[row * MAXNB + s] = lane * 32 + b;
    }
}

// 80 blocks x 1024: fixpoint NMS per class (== greedy), emit candidates.
__global__ __launch_bounds__(1024) void nms_kernel() {
    __shared__ uint32_t skey[N_PROP];
    __shared__ unsigned char state[N_PROP + 16];
    __shared__ uint16_t sdeg[N_PROP];
    __shared__ int s_ch[3];
    __shared__ int s_cnt;
    const int c = blockIdx.x, tid = threadIdx.x;

    if (tid < 500) {
        const float4* srow = (const float4*)&g_scoresT[c * N_PROP];
        float4 v = srow[tid];
        skey[4*tid+0] = fkey(v.x);
        skey[4*tid+1] = fkey(v.y);
        skey[4*tid+2] = fkey(v.z);
        skey[4*tid+3] = fkey(v.w);
        int4 d = ((const int4*)g_deg)[tid];
        sdeg[4*tid+0] = (uint16_t)d.x; state[4*tid+0] = d.x ? ST_UNDEC : ST_KEPT;
        sdeg[4*tid+1] = (uint16_t)d.y; state[4*tid+1] = d.y ? ST_UNDEC : ST_KEPT;
        sdeg[4*tid+2] = (uint16_t)d.z; state[4*tid+2] = d.z ? ST_UNDEC : ST_KEPT;
        sdeg[4*tid+3] = (uint16_t)d.w; state[4*tid+3] = d.w ? ST_UNDEC : ST_KEPT;
    }
    if (tid < 3) s_ch[tid] = 0;
    if (tid == 0) s_cnt = 0;
    __syncthreads();

    // fixpoint: keep[i] <=> no adjacent better j with keep[j]  (== greedy NMS)
    int p = 0;
    for (;;) {
        s_ch[(p+1) % 3] = 0;
        for (int i = tid; i < N_PROP; i += 1024) {
            if (state[i] != ST_UNDEC) continue;
            uint32_t ki = skey[i];
            int deg = sdeg[i];
            bool anyKept = false, anyUndec = false;
            if (deg <= MAXNB) {
                for (int nn = 0; nn < deg; ++nn) {
                    int j = g_nbr[i * MAXNB + nn];
                    uint32_t kj = skey[j];
                    if (kj > ki || (kj == ki && j < i)) {
                        unsigned char stj = state[j];
                        if (stj == ST_KEPT) anyKept = true;
                        else if (stj == ST_UNDEC) anyUndec = true;
                    }
                }
            } else {
                for (int w = 0; w < 64; ++w) {
                    uint32_t bits = g_adj[i * 64 + w];
                    while (bits) {
                        int b = __ffs(bits) - 1; bits &= bits - 1;
                        int j = w * 32 + b;
                        uint32_t kj = skey[j];
                        if (kj > ki || (kj == ki && j < i)) {
                            unsigned char stj = state[j];
                            if (stj == ST_KEPT) anyKept = true;
                            else if (stj == ST_UNDEC) anyUndec = true;
                        }
                    }
                }
            }
            if (anyKept)        { state[i] = ST_SUPP; s_ch[p] = 1; }
            else if (!anyUndec) { state[i] = ST_KEPT; s_ch[p] = 1; }
        }
        __syncthreads();
        if (!s_ch[p]) break;
        p = (p + 1) % 3;
    }

    // persist state (fallback only)
    if (tid < 500)
        ((uint32_t*)&g_state[c * N_PROP])[tid] = ((const uint32_t*)state)[tid];

    // append kept entries with key >= TKEY to THIS CLASS's slots (no cross-block
    // contention; slot order irrelevant — ranking is order-invariant)
    for (int i0 = 0; i0 < N_PROP; i0 += 1024) {
        int i = i0 + tid;
        if (i < N_PROP && state[i] == ST_KEPT && skey[i] >= TKEY) {
            int pos = atomicAdd(&s_cnt, 1);
            if (pos < SLOT) g_scand2[c * SLOT + pos] = packe(skey[i], c, i);
        }
    }
    __syncthreads();
    if (tid == 0) {
        g_ccnt[c] = s_cnt;
        if (s_cnt > SLOT) g_ovf = 1;    // plain store: all writers store 1
    }
}

// select_topt (round-8 proven, 1024 threads) — FALLBACK only.
__device__ void select_topt(const uint32_t* __restrict__ skey,
                            const unsigned char* state, int want,
                            int n, int t,
                            uint32_t* hist, uint32_t* binFill,
                            uint64_t* cand, uint64_t* outbuf, int* sh) {
    const int tid = threadIdx.x;
    const int lane = tid & 63;
    uint32_t prefix = 0, above = 0, thr = 0, Bi = 0, mask = 0x7FFu;
    int shift = 21, width = 11;
    bool tie = false;
    for (;;) {
        for (int b = tid; b <= 2048; b += 1024) hist[b] = 0;
        __syncthreads();
        for (int i0 = 0; i0 < n; i0 += 1024) {
            int i = i0 + tid;
            bool valid = false; uint32_t b = 0;
            if (i < n && (!state || state[i] == want)) {
                uint32_t k = skey[i];
                if (shift == 21 || (k >> (shift + width)) == prefix) {
                    valid = true; b = (k >> shift) & mask;
                }
            }
            uint32_t b0 = __shfl(b, 0);
            bool same = valid && (b == b0);
            unsigned long long eq = __ballot(same);
            if (eq == ~0ull) {
                if (lane == 0) atomicAdd(&hist[b0], 64u);
            } else if (valid) {
                atomicAdd(&hist[b], 1u);
            }
        }
        __syncthreads();
        if (tid < 256) {
            uint32_t c8 = 0;
            #pragma unroll 8
            for (int q = 0; q < 8; ++q) c8 += hist[tid*8 + q];
            binFill[tid] = c8;
        }
        __syncthreads();
        if (tid < 64) {
            uint32_t h0=binFill[4*lane], h1=binFill[4*lane+1], h2=binFill[4*lane+2], h3=binFill[4*lane+3];
            uint32_t T = h0+h1+h2+h3, I = T;
            for (int off = 1; off < 64; off <<= 1) {
                uint32_t v = __shfl_down(I, off);
                if (lane + off < 64) I += v;
            }
            uint32_t S = I - T;
            uint32_t o3=h3+S, o2=h2+o3, o1=h1+o2, o0=h0+o1;
            binFill[4*lane]=o0; binFill[4*lane+1]=o1; binFill[4*lane+2]=o2; binFill[4*lane+3]=o3;
        }
        __syncthreads();
        if (tid < 256) {
            uint32_t run = (tid == 255) ? 0u : binFill[tid+1];
            uint32_t t7,t6,t5,t4,t3,t2,t1,t0;
            run += hist[tid*8+7]; t7 = run;
            run += hist[tid*8+6]; t6 = run;
            run += hist[tid*8+5]; t5 = run;
            run += hist[tid*8+4]; t4 = run;
            run += hist[tid*8+3]; t3 = run;
            run += hist[tid*8+2]; t2 = run;
            run += hist[tid*8+1]; t1 = run;
            run += hist[tid*8+0]; t0 = run;
            hist[tid*8+0]=t0; hist[tid*8+1]=t1; hist[tid*8+2]=t2; hist[tid*8+3]=t3;
            hist[tid*8+4]=t4; hist[tid*8+5]=t5; hist[tid*8+6]=t6; hist[tid*8+7]=t7;
        }
        __syncthreads();
        if (tid < 256) {
            #pragma unroll 8
            for (int q = 0; q < 8; ++q) {
                int b = tid*8 + q;
                uint32_t sb = hist[b], sb1 = hist[b+1];
                if (above + sb >= (uint32_t)t && above + sb1 < (uint32_t)t) sh[1] = b;
            }
        }
        __syncthreads();
        int B = sh[1];
        uint32_t nCand = above + hist[B];
        uint32_t nAbove = above + hist[B+1];
        thr = (prefix << width) | (uint32_t)B;
        if (nCand <= CAP) { __syncthreads(); break; }
        if (shift == 0) {
            uint32_t needS = (uint32_t)t - nAbove;
            __syncthreads();
            for (int b = tid; b < 257; b += 1024) hist[b] = 0;
            __syncthreads();
            for (int i = tid; i < n; i += 1024)
                if ((!state || state[i] == want) && skey[i] == thr)
                    atomicAdd(&hist[i >> 5], 1u);
            __syncthreads();
            if (tid < 64) {
                uint32_t h0=hist[4*lane], h1=hist[4*lane+1], h2=hist[4*lane+2], h3=hist[4*lane+3];
                uint32_t T = h0+h1+h2+h3, I = T;
                for (int off = 1; off < 64; off <<= 1) {
                    uint32_t v = __shfl_up(I, off);
                    if (lane >= off) I += v;
                }
                uint32_t S = I - T;
                uint32_t a0=S+h0, a1=a0+h1, a2=a1+h2, a3=a2+h3;
                hist[4*lane]=a0; hist[4*lane+1]=a1; hist[4*lane+2]=a2; hist[4*lane+3]=a3;
            }
            __syncthreads();
            if (tid < 256) {
                if (hist[tid] >= needS && (tid == 0 || hist[tid-1] < needS)) sh[1] = tid;
            }
            __syncthreads();
            Bi = (uint32_t)sh[1];
            tie = true;
            __syncthreads();
            break;
        }
        prefix = thr; above = nAbove;
        if (shift == 21) { shift = 10; width = 11; mask = 0x7FFu; }
        else             { shift = 0;  width = 10; mask = 0x3FFu; }
        __syncthreads();
    }

    if (!tie && above == 0) {
        for (int b = tid; b < 2048; b += 1024) binFill[b] = 0;
        __syncthreads();
        for (int i = tid; i < n; i += 1024) {
            if (!state || state[i] == want) {
                uint32_t k = skey[i];
                if ((k >> shift) >= thr) {
                    uint32_t be = (k >> shift) & mask;
                    uint32_t pos = hist[be+1] + atomicAdd(&binFill[be], 1u);
                    cand[pos] = ((uint64_t)k << 32) | (uint32_t)(0xFFFFFFFFu - (uint32_t)i);
                }
            }
        }
        __syncthreads();
        int m = (int)hist[thr & mask];
        for (int s = tid; s < m; s += 1024) {
            uint64_t e = cand[s];
            uint32_t k = (uint32_t)(e >> 32);
            uint32_t be = (k >> shift) & mask;
            uint32_t base = hist[be+1];
            uint32_t cnt = hist[be] - base;
            uint32_t r = base;
            for (uint32_t s2 = base; s2 < base + cnt; ++s2)
                r += (cand[s2] > e) ? 1u : 0u;
            if (r < (uint32_t)t) outbuf[r] = e;
        }
        __syncthreads();
    } else {
        if (tid == 0) sh[2] = 0;
        __syncthreads();
        for (int i0 = 0; i0 < n; i0 += 1024) {
            int i = i0 + tid;
            bool take = false; uint32_t k = 0;
            if (i < n && (!state || state[i] == want)) {
                k = skey[i];
                take = tie ? (k > thr || (k == thr && (uint32_t)(i >> 5) <= Bi))
                           : ((k >> shift) >= thr);
            }
            unsigned long long mm = __ballot(take);
            if (mm) {
                int leader = __ffsll((long long)mm) - 1;
                int wbase = 0;
                if (lane == leader) wbase = atomicAdd(&sh[2], (int)__popcll(mm));
                wbase = __shfl(wbase, leader);
                if (take) {
                    int pos = wbase + __popcll(mm & ((1ull << lane) - 1ull));
                    cand[pos] = ((uint64_t)k << 32) | (uint32_t)(0xFFFFFFFFu - (uint32_t)i);
                }
            }
        }
        __syncthreads();
        int m = sh[2];
        for (int s = tid; s < m; s += 1024) {
            uint64_t e = cand[s];
            uint32_t r = 0;
            for (int s2 = 0; s2 < m; ++s2) r += (cand[s2] > e) ? 1u : 0u;
            if (r < (uint32_t)t) outbuf[r] = e;
        }
        __syncthreads();
    }
}

// shared-memory layout (55.7 KB + small arrays)
#define SM_A      0        // fast: dense 0-20480 | cand2 20480-26624
                           // fallback: skey 0-8000 | state 8000-10016 | gkey 0-32000
#define SM_HIST   32000    // 2052*4
#define SM_BINF   40208    // 2048*4
#define SM_OUT    48400    // 304*8
#define SM_SH     50832    // 64
#define SM_CAND   50896    // 768*8 (fallback select_topt)
#define SM_BYTES  57040

// single block x 1024: rank ~625 candidates -> top-300 -> gather output.
__global__ __launch_bounds__(1024) void tail_kernel(float* __restrict__ out) {
    __shared__ __align__(16) char smem[SM_BYTES];
    __shared__ int cnts[NCLS];
    __shared__ int offs[NCLS + 1];
    __shared__ int s_flag;
    uint32_t* hist  = (uint32_t*)(smem + SM_HIST);
    uint32_t* binF  = (uint32_t*)(smem + SM_BINF);
    uint64_t* outbuf= (uint64_t*)(smem + SM_OUT);
    int* sh         = (int*)(smem + SM_SH);
    uint64_t* cand  = (uint64_t*)(smem + SM_CAND);
    const int tid = threadIdx.x;
    const int lane = tid & 63;

    if (tid < NCLS) cnts[tid] = g_ccnt[tid];
    if (tid == 0) s_flag = g_ovf;
    __syncthreads();
    if (tid == 0) {
        int s = 0;
        for (int c = 0; c < NCLS; ++c) {
            offs[c] = s;
            int v = cnts[c]; if (v > SLOT) v = SLOT;
            s += v;
        }
        offs[NCLS] = s;
    }
    __syncthreads();
    const int total = offs[NCLS];
    bool fast = (!s_flag) && (total >= MAXIMG);

    if (fast) {
        uint64_t* dense = (uint64_t*)(smem + SM_A);
        uint64_t* cand2 = (uint64_t*)(smem + SM_A + 20480);
        for (int t2 = tid; t2 < NCLS * SLOT; t2 += 1024) {
            int c = t2 >> 5, j = t2 & (SLOT - 1);
            if (j < cnts[c]) dense[offs[c] + j] = g_scand2[t2];
        }
        for (int b = tid; b <= 2048; b += 1024) hist[b] = 0;
        __syncthreads();
        for (int s = tid; s < total; s += 1024)
            atomicAdd(&hist[cbin2((uint32_t)(dense[s] >> 18))], 1u);
        __syncthreads();
        // suffix scan of hist[0..2047]
        if (tid < 256) {
            uint32_t c8 = 0;
            #pragma unroll 8
            for (int q = 0; q < 8; ++q) c8 += hist[tid*8 + q];
            binF[tid] = c8;
        }
        __syncthreads();
        if (tid < 64) {
            uint32_t h0=binF[4*lane], h1=binF[4*lane+1], h2=binF[4*lane+2], h3=binF[4*lane+3];
            uint32_t T = h0+h1+h2+h3, I = T;
            for (int off = 1; off < 64; off <<= 1) {
                uint32_t v = __shfl_down(I, off);
                if (lane + off < 64) I += v;
            }
            uint32_t S = I - T;
            uint32_t o3=h3+S, o2=h2+o3, o1=h1+o2, o0=h0+o1;
            binF[4*lane]=o0; binF[4*lane+1]=o1; binF[4*lane+2]=o2; binF[4*lane+3]=o3;
        }
        __syncthreads();
        if (tid < 256) {
            uint32_t run = (tid == 255) ? 0u : binF[tid+1];
            uint32_t t7,t6,t5,t4,t3,t2,t1,t0;
            run += hist[tid*8+7]; t7 = run;
            run += hist[tid*8+6]; t6 = run;
            run += hist[tid*8+5]; t5 = run;
            run += hist[tid*8+4]; t4 = run;
            run += hist[tid*8+3]; t3 = run;
            run += hist[tid*8+2]; t2 = run;
            run += hist[tid*8+1]; t1 = run;
            run += hist[tid*8+0]; t0 = run;
            hist[tid*8+0]=t0; hist[tid*8+1]=t1; hist[tid*8+2]=t2; hist[tid*8+3]=t3;
            hist[tid*8+4]=t4; hist[tid*8+5]=t5; hist[tid*8+6]=t6; hist[tid*8+7]=t7;
        }
        __syncthreads();
        if (tid < 256) {
            #pragma unroll 8
            for (int q = 0; q < 8; ++q) {
                int b = tid*8 + q;
                if (hist[b] >= (uint32_t)MAXIMG && hist[b+1] < (uint32_t)MAXIMG) sh[1] = b;
            }
        }
        __syncthreads();
        const int B = sh[1];
        const int nCand = (int)hist[B];
        if (nCand > CAPT) { fast = false; }
        if (fast) {
            for (int b = tid; b < 2048; b += 1024) binF[b] = 0;
            __syncthreads();
            for (int s = tid; s < total; s += 1024) {
                uint64_t e = dense[s];
                uint32_t b = cbin2((uint32_t)(e >> 18));
                if (b >= (uint32_t)B) {
                    uint32_t pos = hist[b+1] + atomicAdd(&binF[b], 1u);
                    cand2[pos] = e;
                }
            }
            __syncthreads();
            for (int s = tid; s < nCand; s += 1024) {
                uint64_t e = cand2[s];
                uint32_t b = cbin2((uint32_t)(e >> 18));
                uint32_t base = hist[b+1];
                uint32_t cnt2 = hist[b] - base;
                uint32_t r = base;
                for (uint32_t s2 = base; s2 < base + cnt2; ++s2)
                    r += (cand2[s2] > e) ? 1u : 0u;
                if (r < (uint32_t)MAXIMG) outbuf[r] = e;
            }
            __syncthreads();
            // winners' in-class ranks < SLOT(32) < 100 by construction: no cap check
            if (tid < MAXIMG) {
                uint64_t e = outbuf[tid];
                int i = 2047 - (int)(e & 0x7FF);
                int wc = 127 - (int)((e >> 11) & 0x7F);
                float4 b = g_boxes[i];
                out[tid*4+0] = b.x;
                out[tid*4+1] = b.y;
                out[tid*4+2] = b.z;
                out[tid*4+3] = b.w;
                out[MAXIMG*4 + tid] = (float)wc;
            }
            return;
        }
        __syncthreads();
    }

    // ============ FALLBACK (correctness net; never runs on bench data) ============
    uint32_t* skey  = (uint32_t*)(smem + SM_A);
    unsigned char* state = (unsigned char*)(smem + SM_A + 8000);
    for (int c2 = 0; c2 < NCLS; ++c2) {
        if (tid < 500) {
            const float4* srow = (const float4*)&g_scoresT[c2 * N_PROP];
            float4 v = srow[tid];
            skey[4*tid+0] = fkey(v.x);
            skey[4*tid+1] = fkey(v.y);
            skey[4*tid+2] = fkey(v.z);
            skey[4*tid+3] = fkey(v.w);
            ((uint32_t*)state)[tid] = ((const uint32_t*)&g_state[c2 * N_PROP])[tid];
        }
        if (tid == 0) sh[5] = 0;
        __syncthreads();
        {
            int local = 0;
            for (int i = tid; i < N_PROP; i += 1024) local += (state[i] == ST_KEPT) ? 1 : 0;
            if (local) atomicAdd(&sh[5], local);
        }
        __syncthreads();
        const int kept = sh[5];
        const int t1 = kept < MAXPC ? kept : MAXPC;
        select_topt(skey, state, ST_KEPT, N_PROP, t1, hist, binF, cand, outbuf, sh);
        for (int r = tid; r < t1; r += 1024) {
            uint64_t e = outbuf[r];
            g_outkey[c2 * MAXPC + r] = (uint32_t)(e >> 32);
            g_outidx[c2 * MAXPC + r] = (int)(0xFFFFFFFFu - (uint32_t)e);
        }
        if (kept < MAXPC) {
            __syncthreads();
            const int t2 = MAXPC - kept;
            select_topt(skey, state, ST_SUPP, N_PROP, t2, hist, binF, cand, outbuf, sh);
            for (int r = tid; r < t2; r += 1024) {
                uint64_t e = outbuf[r];
                g_outkey[c2 * MAXPC + kept + r] = FKEY_NEGINF;
                g_outidx[c2 * MAXPC + kept + r] = (int)(0xFFFFFFFFu - (uint32_t)e);
            }
        }
        __syncthreads();
    }
    {
        uint32_t* gkey = (uint32_t*)(smem + SM_A);
        const uint4* gk4 = (const uint4*)g_outkey;
        uint4* lk4 = (uint4*)gkey;
        for (int q = tid; q < NFLAT/4; q += 1024) lk4[q] = gk4[q];
        __syncthreads();
        select_topt(gkey, nullptr, 0, NFLAT, MAXIMG, hist, binF, cand, outbuf, sh);
        for (int r = tid; r < MAXIMG; r += 1024) {
            uint64_t e = outbuf[r];
            int f = (int)(0xFFFFFFFFu - (uint32_t)e);
            int pi = g_outidx[f];
            float4 b = g_boxes[pi];
            out[r*4+0] = b.x;
            out[r*4+1] = b.y;
            out[r*4+2] = b.z;
            out[r*4+3] = b.w;
            out[MAXIMG*4 + r] = (float)(f / MAXPC);
        }
    }
}

extern "C" void kernel_launch(void* const* d_in, const int* in_sizes, int n_in,
                              void* d_out, int out_size, void* d_ws, size_t ws_size,
                              hipStream_t stream) {
    const float* deltas = (const float*)d_in[0];   // roi_bboxes_txtytwth [2000,4]
    const float* scores = (const float*)d_in[1];   // roi_score [2000,80]
    const float* props  = (const float*)d_in[2];   // rpn_proposals_bboxes [2000,4]
    float* out = (float*)d_out;                    // 1200 box floats + 300 class floats

    adj_kernel<<<125, 1024, 0, stream>>>(deltas, props, scores);
    nms_kernel<<<NCLS, 1024, 0, stream>>>();
    tail_kernel<<<1, 1024, 0, stream>>>(out);
}